// Round 1
// baseline (3769.870 us; speedup 1.0000x reference)
//
#include <hip/hip_runtime.h>

#define INPUT 64
#define HID 256
#define BATCH 128
#define TSTEPS 1000
#define KTOT 320            // 256 (h) + 64 (x)

typedef __bf16 bf16_t;
typedef __bf16 bf16x8 __attribute__((ext_vector_type(8)));
typedef float  f32x4  __attribute__((ext_vector_type(4)));

// ---- ws layout (bytes) ----
#define WPACK_OFF   0
#define WPACK_BYTES (1024 * KTOT * 2)            // 655360
#define BIAS_OFF    (WPACK_OFF + WPACK_BYTES)
#define BIAS_BYTES  (1024 * 4)
#define EXCH_OFF    (BIAS_OFF + BIAS_BYTES)      // 32 bufs x 16x128 bf16
#define EXCH_BYTES  (32 * 2048 * 2)
#define FLAG_OFF    (EXCH_OFF + EXCH_BYTES)      // 16 flags, 64B apart

__global__ void lstm_prep(
    const float* __restrict__ Wii, const float* __restrict__ Wif,
    const float* __restrict__ Wig, const float* __restrict__ Wio,
    const float* __restrict__ Whi, const float* __restrict__ Whf,
    const float* __restrict__ Whg, const float* __restrict__ Who,
    const float* __restrict__ bii, const float* __restrict__ bif,
    const float* __restrict__ big, const float* __restrict__ bio,
    const float* __restrict__ bhi, const float* __restrict__ bhf,
    const float* __restrict__ bhg, const float* __restrict__ bho,
    bf16_t* __restrict__ wpack, float* __restrict__ bias,
    int* __restrict__ flags)
{
    int id = blockIdx.x * 256 + threadIdx.x;
    if (id < 1024 * KTOT) {
        int n = id / KTOT, k = id % KTOT;
        int g = n >> 8, j = n & 255;
        const float* Wh = (g == 0) ? Whi : (g == 1) ? Whf : (g == 2) ? Whg : Who;
        const float* Wi = (g == 0) ? Wii : (g == 1) ? Wif : (g == 2) ? Wig : Wio;
        float v = (k < HID) ? Wh[j * HID + k] : Wi[j * INPUT + (k - HID)];
        wpack[id] = (bf16_t)v;
    }
    if (id < 1024) {
        int g = id >> 8, j = id & 255;
        const float* bi = (g == 0) ? bii : (g == 1) ? bif : (g == 2) ? big : bio;
        const float* bh = (g == 0) ? bhi : (g == 1) ? bhf : (g == 2) ? bhg : bho;
        bias[id] = bi[j] + bh[j];
    }
    if (id < 16) flags[id * 16] = 0;
}

__device__ __forceinline__ float sigmoid_f(float v) {
    return 1.0f / (1.0f + __expf(-v));
}
__device__ __forceinline__ float tanh_f(float v) {
    return 1.0f - 2.0f / (__expf(2.0f * v) + 1.0f);
}

// 16 blocks: group = blockIdx&7, half = blockIdx>>3 (pair b, b+8 -> same XCD)
__global__ __launch_bounds__(512, 2) void lstm_main(
    const float* __restrict__ x, const bf16_t* __restrict__ wpack,
    const float* __restrict__ bias_g, float* __restrict__ out,
    bf16_t* __restrict__ exch, int* __restrict__ flags)
{
    __shared__ bf16_t hx[16 * 136];      // local h half: [16][128] pad->136
    __shared__ bf16_t xb[2 * 16 * 72];   // x stage dbuf:  [2][16][64] pad->72

    const int wg    = blockIdx.x;
    const int group = wg & 7;
    const int half  = wg >> 3;
    const int tid   = threadIdx.x;
    const int w     = tid >> 6;          // wave 0..7
    const int l     = tid & 63;
    const int col   = l & 15;
    const int kb    = l >> 4;            // 0..3

    const int jrel  = w * 16 + col;            // 0..127
    const int jglob = half * 128 + jrel;       // 0..255

    // ---- persistent B fragments (weights), role-indexed (static!) ----
    bf16x8 bL[4][4], bP[4][4], bX[4][2];
    const int lbase = half * 128;
    const int pbase = (1 - half) * 128;
#pragma unroll
    for (int gt = 0; gt < 4; ++gt) {
        const bf16_t* wrow = wpack + (size_t)(gt * 256 + jglob) * KTOT;
#pragma unroll
        for (int i = 0; i < 4; ++i) {
            bL[gt][i] = *(const bf16x8*)(wrow + lbase + i * 32 + kb * 8);
            bP[gt][i] = *(const bf16x8*)(wrow + pbase + i * 32 + kb * 8);
        }
#pragma unroll
        for (int i = 0; i < 2; ++i)
            bX[gt][i] = *(const bf16x8*)(wrow + 256 + i * 32 + kb * 8);
    }
    float bias_r[4];
#pragma unroll
    for (int gt = 0; gt < 4; ++gt) bias_r[gt] = bias_g[gt * 256 + jglob];

    float c_st[4] = {0.f, 0.f, 0.f, 0.f};

    const int me = group * 2 + half;
    const int pn = group * 2 + (1 - half);
    int* flag_me = flags + me * 16;
    int* flag_pn = flags + pn * 16;

    // prologue: stage x_0 into xb[0]
    {
        int b = tid >> 5, i0 = (tid & 31) * 2;
        const float* xp = x + (size_t)(group * 16 + b) * (TSTEPS * INPUT) + i0;
        float2 v = *(const float2*)xp;
        xb[b * 72 + i0]     = (bf16_t)v.x;
        xb[b * 72 + i0 + 1] = (bf16_t)v.y;
    }

    for (int t = 0; t < TSTEPS; ++t) {
        __syncthreads();                                   // (1) x_t, h_{t-1} ready
        const int par = t & 1;

        f32x4 acc[4];
#pragma unroll
        for (int gt = 0; gt < 4; ++gt)
            acc[gt] = (f32x4){bias_r[gt], bias_r[gt], bias_r[gt], bias_r[gt]};

        // x-part (K slices 8,9)
        {
            const bf16_t* xrow = xb + par * 1152 + (l & 15) * 72 + kb * 8;
            bf16x8 a0 = *(const bf16x8*)(xrow);
            bf16x8 a1 = *(const bf16x8*)(xrow + 32);
#pragma unroll
            for (int gt = 0; gt < 4; ++gt) {
                acc[gt] = __builtin_amdgcn_mfma_f32_16x16x32_bf16(a0, bX[gt][0], acc[gt], 0, 0, 0);
                acc[gt] = __builtin_amdgcn_mfma_f32_16x16x32_bf16(a1, bX[gt][1], acc[gt], 0, 0, 0);
            }
        }
        // local h half
        if (t > 0) {
            bf16x8 aL[4];
#pragma unroll
            for (int i = 0; i < 4; ++i)
                aL[i] = *(const bf16x8*)(hx + (l & 15) * 136 + i * 32 + kb * 8);
#pragma unroll
            for (int gt = 0; gt < 4; ++gt) {
#pragma unroll
                for (int i = 0; i < 4; ++i)
                    acc[gt] = __builtin_amdgcn_mfma_f32_16x16x32_bf16(aL[i], bL[gt][i], acc[gt], 0, 0, 0);
            }
        }
        // stage x_{t+1} into the other parity buffer (hides HBM latency)
        if (t + 1 < TSTEPS) {
            int b = tid >> 5, i0 = (tid & 31) * 2;
            const float* xp = x + (size_t)(group * 16 + b) * (TSTEPS * INPUT) + (size_t)(t + 1) * INPUT + i0;
            float2 v = *(const float2*)xp;
            xb[(par ^ 1) * 1152 + b * 72 + i0]     = (bf16_t)v.x;
            xb[(par ^ 1) * 1152 + b * 72 + i0 + 1] = (bf16_t)v.y;
        }
        // partner h half (via L2 exchange)
        if (t > 0) {
            if (tid == 0) {
                while (__hip_atomic_load(flag_pn, __ATOMIC_ACQUIRE, __HIP_MEMORY_SCOPE_AGENT) < t) {}
            }
            __syncthreads();                               // (2) partner h_{t-1} visible
            const bf16_t* bufR = exch + (size_t)(pn * 2 + ((t - 1) & 1)) * 2048;
            bf16x8 aP[4];
#pragma unroll
            for (int i = 0; i < 4; ++i)
                aP[i] = *(const bf16x8*)(bufR + (l & 15) * 128 + i * 32 + kb * 8);
#pragma unroll
            for (int gt = 0; gt < 4; ++gt) {
#pragma unroll
                for (int i = 0; i < 4; ++i)
                    acc[gt] = __builtin_amdgcn_mfma_f32_16x16x32_bf16(aP[i], bP[gt][i], acc[gt], 0, 0, 0);
            }
        }
        __syncthreads();                                   // (3) all hx reads done

        // epilogue: gates -> c,h ; publish h
        bf16_t* bufW = exch + (size_t)(me * 2 + par) * 2048;
#pragma unroll
        for (int r = 0; r < 4; ++r) {
            int be = kb * 4 + r;                           // batch row in group
            float gi = sigmoid_f(acc[0][r]);
            float gf = sigmoid_f(acc[1][r]);
            float gg = tanh_f(acc[2][r]);
            float go = sigmoid_f(acc[3][r]);
            float c  = gf * c_st[r] + gi * gg;
            c_st[r]  = c;
            float h  = go * tanh_f(c);
            bf16_t hb = (bf16_t)h;
            hx[be * 136 + jrel]   = hb;                    // local A for next step
            bufW[be * 128 + jrel] = hb;                    // partner's A for next step
            int bg = group * 16 + be;
            out[((size_t)bg * TSTEPS + t) * HID + jglob] = h;
            if (t == TSTEPS - 1) {
                out[(size_t)BATCH * TSTEPS * HID + (size_t)bg * HID + jglob] = h;
                out[(size_t)BATCH * TSTEPS * HID + (size_t)BATCH * HID + (size_t)bg * HID + jglob] = c;
            }
        }
        __syncthreads();                                   // (4) buf stores drained
        if (tid == 0)
            __hip_atomic_store(flag_me, t + 1, __ATOMIC_RELEASE, __HIP_MEMORY_SCOPE_AGENT);
    }
}

extern "C" void kernel_launch(void* const* d_in, const int* in_sizes, int n_in,
                              void* d_out, int out_size, void* d_ws, size_t ws_size,
                              hipStream_t stream)
{
    (void)in_sizes; (void)n_in; (void)out_size; (void)ws_size;
    const float* x   = (const float*)d_in[0];
    const float* Wii = (const float*)d_in[1];
    const float* bii = (const float*)d_in[2];
    const float* Wif = (const float*)d_in[3];
    const float* bif = (const float*)d_in[4];
    const float* Wig = (const float*)d_in[5];
    const float* big = (const float*)d_in[6];
    const float* Wio = (const float*)d_in[7];
    const float* bio = (const float*)d_in[8];
    const float* Whi = (const float*)d_in[9];
    const float* bhi = (const float*)d_in[10];
    const float* Whf = (const float*)d_in[11];
    const float* bhf = (const float*)d_in[12];
    const float* Whg = (const float*)d_in[13];
    const float* bhg = (const float*)d_in[14];
    const float* Who = (const float*)d_in[15];
    const float* bho = (const float*)d_in[16];

    char* ws = (char*)d_ws;
    bf16_t* wpack = (bf16_t*)(ws + WPACK_OFF);
    float*  bias  = (float*)(ws + BIAS_OFF);
    bf16_t* exch  = (bf16_t*)(ws + EXCH_OFF);
    int*    flags = (int*)(ws + FLAG_OFF);

    lstm_prep<<<(1024 * KTOT + 255) / 256, 256, 0, stream>>>(
        Wii, Wif, Wig, Wio, Whi, Whf, Whg, Who,
        bii, bif, big, bio, bhi, bhf, bhg, bho,
        wpack, bias, flags);

    lstm_main<<<16, 512, 0, stream>>>(
        x, wpack, bias, (float*)d_out, exch, flags);
}